// Round 4
// baseline (323.638 us; speedup 1.0000x reference)
//
#include <hip/hip_runtime.h>

#define SS 2048
#define DD 1024
#define HH 16
#define DEPTH 64
#define WINDOW 64
#define NTOK 32
#define KV_ELEMS (NTOK*SS*DD)      // 67,108,864 floats per tensor
#define N4 (KV_ELEMS/4)            // 16,777,216 f4 per tensor (2^24)
#define CPT 524288                 // copy threads per kernel (2^19)

// ws layout (floats)
#define WS_Q 0
#define WS_K (NTOK*DD)
#define WS_V (2*NTOK*DD)
#define WS_Z (3*NTOK*DD)

typedef float f4 __attribute__((ext_vector_type(4)));

// Copy one full KV tensor (2^24 f4) with 2^19 threads: 8 sweeps x 4 unrolled.
// Plain loads (keep L2/L3 assist), nontemporal stores, skip row t (proj owns it).
__device__ __forceinline__ void copy_tensor(const float* __restrict__ src,
                                            float* __restrict__ dst,
                                            int t, int lin) {
    const f4* __restrict__ s4 = (const f4*)src;
    f4* __restrict__ d4 = (f4*)dst;
    int i = lin;
    #pragma unroll
    for (int sweep = 0; sweep < 8; ++sweep) {
        const int i0 = i, i1 = i + CPT, i2 = i + 2 * CPT, i3 = i + 3 * CPT;
        const f4 v0 = s4[i0];
        const f4 v1 = s4[i1];
        const f4 v2 = s4[i2];
        const f4 v3 = s4[i3];
        if (((i0 >> 8) & (SS - 1)) != t) __builtin_nontemporal_store(v0, d4 + i0);
        if (((i1 >> 8) & (SS - 1)) != t) __builtin_nontemporal_store(v1, d4 + i1);
        if (((i2 >> 8) & (SS - 1)) != t) __builtin_nontemporal_store(v2, d4 + i2);
        if (((i3 >> 8) & (SS - 1)) != t) __builtin_nontemporal_store(v3, d4 + i3);
        i += 4 * CPT;
    }
}

// ------------- kernel 1: column-parallel QKV proj + copy of K tensor --------
#define NPROJ 48     // 3 matrices x 16 col-chunks of 64
#define K1CB  1024   // copy blocks (512 thr): 2^19 threads

__global__ __launch_bounds__(512)
void k1_proj_copyK(const float* __restrict__ x,
                   const float* __restrict__ K,
                   const float* __restrict__ Wq, const float* __restrict__ bq,
                   const float* __restrict__ Wk, const float* __restrict__ bk,
                   const float* __restrict__ Wv, const float* __restrict__ bv,
                   const int* __restrict__ tptr,
                   float* __restrict__ ws,
                   float* __restrict__ outK, float* __restrict__ outV) {
    const int t = *tptr;
    if (blockIdx.x >= NPROJ) {
        copy_tensor(K, outK, t, (blockIdx.x - NPROJ) * 512 + (int)threadIdx.x);
        return;
    }
    __shared__ __align__(16) float xs[NTOK][128];
    const int m     = blockIdx.x >> 4;       // 0:q 1:k 2:v
    const int chunk = blockIdx.x & 15;       // 64-col chunk
    const float* __restrict__ W  = (m == 0) ? Wq : (m == 1) ? Wk : Wv;
    const float* __restrict__ bb = (m == 0) ? bq : (m == 1) ? bk : bv;
    const int lane = threadIdx.x & 63;
    const int tg   = threadIdx.x >> 6;       // 0..7 -> tokens tg*4..tg*4+3
    const int j    = chunk * 64 + lane;
    const int tok0 = tg * 4;

    float acc0, acc1, acc2, acc3;
    acc0 = acc1 = acc2 = acc3 = bb[j];

    for (int c = 0; c < 8; ++c) {            // 8 row chunks of 128
        __syncthreads();
        for (int r = threadIdx.x; r < NTOK * 32; r += 512) {
            const int tok = r >> 5, q4 = r & 31;
            ((f4*)xs[tok])[q4] = ((const f4*)(x + (size_t)tok * DD + c * 128))[q4];
        }
        __syncthreads();
        const float* Wc = W + (size_t)(c * 128) * DD + j;
        #pragma unroll 2
        for (int il4 = 0; il4 < 32; ++il4) {
            const int il = il4 * 4;
            const float w0 = Wc[(size_t)(il + 0) * DD];
            const float w1 = Wc[(size_t)(il + 1) * DD];
            const float w2 = Wc[(size_t)(il + 2) * DD];
            const float w3 = Wc[(size_t)(il + 3) * DD];
            const f4 x0 = ((const f4*)xs[tok0 + 0])[il4];
            const f4 x1 = ((const f4*)xs[tok0 + 1])[il4];
            const f4 x2 = ((const f4*)xs[tok0 + 2])[il4];
            const f4 x3 = ((const f4*)xs[tok0 + 3])[il4];
            acc0 = fmaf(w3, x0.w, fmaf(w2, x0.z, fmaf(w1, x0.y, fmaf(w0, x0.x, acc0))));
            acc1 = fmaf(w3, x1.w, fmaf(w2, x1.z, fmaf(w1, x1.y, fmaf(w0, x1.x, acc1))));
            acc2 = fmaf(w3, x2.w, fmaf(w2, x2.z, fmaf(w1, x2.y, fmaf(w0, x2.x, acc2))));
            ac3:
            acc3 = fmaf(w3, x3.w, fmaf(w2, x3.z, fmaf(w1, x3.y, fmaf(w0, x3.x, acc3))));
        }
    }
    float* dst = ws + m * (NTOK * DD);
    dst[(size_t)(tok0 + 0) * DD + j] = acc0;
    dst[(size_t)(tok0 + 1) * DD + j] = acc1;
    dst[(size_t)(tok0 + 2) * DD + j] = acc2;
    dst[(size_t)(tok0 + 3) * DD + j] = acc3;
    if (m == 1) {
        outK[((size_t)(tok0 + 0) * SS + t) * DD + j] = acc0;
        outK[((size_t)(tok0 + 1) * SS + t) * DD + j] = acc1;
        outK[((size_t)(tok0 + 2) * SS + t) * DD + j] = acc2;
        outK[((size_t)(tok0 + 3) * SS + t) * DD + j] = acc3;
    } else if (m == 2) {
        outV[((size_t)(tok0 + 0) * SS + t) * DD + j] = acc0;
        outV[((size_t)(tok0 + 1) * SS + t) * DD + j] = acc1;
        outV[((size_t)(tok0 + 2) * SS + t) * DD + j] = acc2;
        outV[((size_t)(tok0 + 3) * SS + t) * DD + j] = acc3;
    }
}

// ------- kernel 2: per-token {attention -> out-proj} + copy of V tensor -----
#define K2CB 512     // copy blocks (1024 thr): 2^19 threads

__global__ __launch_bounds__(1024)
void k2_attn_out_copyV(const float* __restrict__ K, const float* __restrict__ V,
                       const float* __restrict__ Wo, const float* __restrict__ bo,
                       const int* __restrict__ tptr,
                       float* __restrict__ ws,
                       float* __restrict__ outZ, float* __restrict__ outA,
                       float* __restrict__ outV) {
    const int t = *tptr;
    if (blockIdx.x >= NTOK) {
        copy_tensor(V, outV, t, (blockIdx.x - NTOK) * 1024 + (int)threadIdx.x);
        return;
    }
    const int tok  = blockIdx.x;
    const int tid  = threadIdx.x;
    const int wv   = tid >> 6;               // head
    const int lane = tid & 63;

    __shared__ float qs[DD], ks[DD], vs[DD], zs[DD];
    __shared__ float sc[HH][WINDOW + 8];

    qs[tid] = ws[WS_Q + (size_t)tok * DD + tid];
    ks[tid] = ws[WS_K + (size_t)tok * DD + tid];
    vs[tid] = ws[WS_V + (size_t)tok * DD + tid];
    __syncthreads();

    const int lo    = (t > WINDOW) ? (t - WINDOW) : 0;
    const int count = t - lo + 1;            // <= 65
    const size_t kvbase = (size_t)tok * SS * DD + wv * DEPTH;
    const int hbase = wv * DEPTH;

    // logits for window positions (lane j handles position lo+j)
    for (int jj = lane; jj < count; jj += 64) {
        const int s = lo + jj;
        float acc = 0.f;
        if (s == t) {
            #pragma unroll
            for (int d = 0; d < DEPTH; ++d)
                acc = fmaf(qs[hbase + d], ks[hbase + d], acc);
        } else {
            const f4* kr = (const f4*)(K + kvbase + (size_t)s * DD);
            #pragma unroll
            for (int d4 = 0; d4 < DEPTH / 4; ++d4) {
                const f4 kk = kr[d4];
                acc = fmaf(qs[hbase + d4 * 4 + 0], kk.x, acc);
                acc = fmaf(qs[hbase + d4 * 4 + 1], kk.y, acc);
                acc = fmaf(qs[hbase + d4 * 4 + 2], kk.z, acc);
                acc = fmaf(qs[hbase + d4 * 4 + 3], kk.w, acc);
            }
        }
        sc[wv][jj] = acc * 0.125f;           // 1/sqrt(64)
    }

    // wave softmax (per-wave LDS region; intra-wave ordering)
    float mx = -1e30f;
    for (int jj = lane; jj < count; jj += 64) mx = fmaxf(mx, sc[wv][jj]);
    #pragma unroll
    for (int o = 32; o; o >>= 1) mx = fmaxf(mx, __shfl_xor(mx, o));
    float sum = 0.f;
    for (int jj = lane; jj < count; jj += 64) {
        const float e = expf(sc[wv][jj] - mx);
        sc[wv][jj] = e;
        sum += e;
    }
    #pragma unroll
    for (int o = 32; o; o >>= 1) sum += __shfl_xor(sum, o);
    const float inv = 1.f / sum;
    for (int jj = lane; jj < count; jj += 64) sc[wv][jj] *= inv;

    // full attn row (zeros outside window)
    {
        f4* oa = (f4*)(outA + ((size_t)tok * HH + wv) * SS);
        for (int q4 = lane; q4 < SS / 4; q4 += 64) {
            const int s0 = q4 * 4;
            f4 val;
            val.x = (s0 + 0 >= lo && s0 + 0 <= t) ? sc[wv][s0 + 0 - lo] : 0.f;
            val.y = (s0 + 1 >= lo && s0 + 1 <= t) ? sc[wv][s0 + 1 - lo] : 0.f;
            val.z = (s0 + 2 >= lo && s0 + 2 <= t) ? sc[wv][s0 + 2 - lo] : 0.f;
            val.w = (s0 + 3 >= lo && s0 + 3 <= t) ? sc[wv][s0 + 3 - lo] : 0.f;
            __builtin_nontemporal_store(val, oa + q4);
        }
    }

    // z[head][lane] = sum_s p[s] * V[s][head*64+lane]
    {
        float acc = 0.f;
        #pragma unroll 4
        for (int jj = 0; jj < count - 1; ++jj)
            acc = fmaf(sc[wv][jj], V[kvbase + (size_t)(lo + jj) * DD + lane], acc);
        acc = fmaf(sc[wv][count - 1], vs[hbase + lane], acc);
        zs[hbase + lane] = acc;
    }
    __syncthreads();

    // out-projection: column tid of z @ Wo + bo (Wo rows coalesced across block)
    {
        float ao = bo[tid];
        #pragma unroll 8
        for (int i2 = 0; i2 < DD; ++i2)
            ao = fmaf(zs[i2], Wo[(size_t)i2 * DD + tid], ao);
        outZ[(size_t)tok * DD + tid] = ao;
    }
}

extern "C" void kernel_launch(void* const* d_in, const int* in_sizes, int n_in,
                              void* d_out, int out_size, void* d_ws, size_t ws_size,
                              hipStream_t stream) {
    const float* x  = (const float*)d_in[0];
    const float* K  = (const float*)d_in[1];
    const float* V  = (const float*)d_in[2];
    const float* Wq = (const float*)d_in[3];
    const float* bq = (const float*)d_in[4];
    const float* Wk = (const float*)d_in[5];
    const float* bk = (const float*)d_in[6];
    const float* Wv = (const float*)d_in[7];
    const float* bv = (const float*)d_in[8];
    const float* Wo = (const float*)d_in[9];
    const float* bo = (const float*)d_in[10];
    const int* tptr = (const int*)d_in[11];

    float* out  = (float*)d_out;
    float* outZ = out;                 // (B,P,1,D)   32,768
    float* outK = out + 32768;         // (B,P,S,D)   67,108,864
    float* outV = outK + KV_ELEMS;     // (B,P,S,D)   67,108,864
    float* outA = outV + KV_ELEMS;     // (B,P,H,1,S) 1,048,576
    float* ws   = (float*)d_ws;

    k1_proj_copyK<<<NPROJ + K1CB, 512, 0, stream>>>(
        x, K, Wq, bq, Wk, bk, Wv, bv, tptr, ws, outK, outV);
    k2_attn_out_copyV<<<NTOK + K2CB, 1024, 0, stream>>>(
        K, V, Wo, bo, tptr, ws, outZ, outA, outV);
}

// Round 5
// 234.959 us; speedup vs baseline: 1.3774x; 1.3774x over previous
//
#include <hip/hip_runtime.h>

#define SS 2048
#define DD 1024
#define HH 16
#define DEPTH 64
#define WINDOW 64
#define NTOK 32
#define KV_ELEMS (NTOK*SS*DD)      // 67,108,864 floats per tensor
#define N4 (KV_ELEMS/4)            // 16,777,216 f4 per tensor

// ws layout (floats)
#define WS_Q 0
#define WS_K (NTOK*DD)
#define WS_V (2*NTOK*DD)
#define WS_Z (3*NTOK*DD)

typedef float f4 __attribute__((ext_vector_type(4)));

// R3-proven copy: nontemporal load+store, dense grid-stride, skip row t.
__device__ __forceinline__ void copy_tensor(const float* __restrict__ src,
                                            float* __restrict__ dst,
                                            int t, int cbid, int ncblk, int nthr) {
    const f4* __restrict__ s4 = (const f4*)src;
    f4* __restrict__ d4 = (f4*)dst;
    const int stride = ncblk * nthr;
    for (int i = cbid * nthr + (int)threadIdx.x; i < N4; i += stride) {
        if (((i >> 8) & (SS - 1)) == t) continue;   // 256 f4 per seq row
        f4 val = __builtin_nontemporal_load(s4 + i);
        __builtin_nontemporal_store(val, d4 + i);
    }
}

// ------------- kernel 1: column-parallel QKV proj + copy of K tensor --------
#define NPROJ 48     // 3 matrices x 16 col-chunks of 64
#define K1CB  976    // copy blocks @512 thr (total 1024 blocks = 4/CU exactly)

__global__ __launch_bounds__(512)
void k1_proj_copyK(const float* __restrict__ x,
                   const float* __restrict__ K,
                   const float* __restrict__ Wq, const float* __restrict__ bq,
                   const float* __restrict__ Wk, const float* __restrict__ bk,
                   const float* __restrict__ Wv, const float* __restrict__ bv,
                   const int* __restrict__ tptr,
                   float* __restrict__ ws,
                   float* __restrict__ outK, float* __restrict__ outV) {
    const int t = *tptr;
    if (blockIdx.x >= NPROJ) {
        copy_tensor(K, outK, t, blockIdx.x - NPROJ, gridDim.x - NPROJ, 512);
        return;
    }
    __shared__ __align__(16) float xs[NTOK][128];
    const int m     = blockIdx.x >> 4;       // 0:q 1:k 2:v
    const int chunk = blockIdx.x & 15;       // 64-col chunk
    const float* __restrict__ W  = (m == 0) ? Wq : (m == 1) ? Wk : Wv;
    const float* __restrict__ bb = (m == 0) ? bq : (m == 1) ? bk : bv;
    const int lane = threadIdx.x & 63;
    const int tg   = threadIdx.x >> 6;       // 0..7 -> tokens tg*4..tg*4+3
    const int j    = chunk * 64 + lane;
    const int tok0 = tg * 4;

    float acc0, acc1, acc2, acc3;
    acc0 = acc1 = acc2 = acc3 = bb[j];

    for (int c = 0; c < 8; ++c) {            // 8 row chunks of 128
        __syncthreads();
        for (int r = threadIdx.x; r < NTOK * 32; r += 512) {
            const int tok = r >> 5, q4 = r & 31;
            ((f4*)xs[tok])[q4] = ((const f4*)(x + (size_t)tok * DD + c * 128))[q4];
        }
        __syncthreads();
        const float* Wc = W + (size_t)(c * 128) * DD + j;
        #pragma unroll 2
        for (int il4 = 0; il4 < 32; ++il4) {
            const int il = il4 * 4;
            const float w0 = Wc[(size_t)(il + 0) * DD];
            const float w1 = Wc[(size_t)(il + 1) * DD];
            const float w2 = Wc[(size_t)(il + 2) * DD];
            const float w3 = Wc[(size_t)(il + 3) * DD];
            const f4 x0 = ((const f4*)xs[tok0 + 0])[il4];
            const f4 x1 = ((const f4*)xs[tok0 + 1])[il4];
            const f4 x2 = ((const f4*)xs[tok0 + 2])[il4];
            const f4 x3 = ((const f4*)xs[tok0 + 3])[il4];
            acc0 = fmaf(w3, x0.w, fmaf(w2, x0.z, fmaf(w1, x0.y, fmaf(w0, x0.x, acc0))));
            acc1 = fmaf(w3, x1.w, fmaf(w2, x1.z, fmaf(w1, x1.y, fmaf(w0, x1.x, acc1))));
            acc2 = fmaf(w3, x2.w, fmaf(w2, x2.z, fmaf(w1, x2.y, fmaf(w0, x2.x, acc2))));
            acc3 = fmaf(w3, x3.w, fmaf(w2, x3.z, fmaf(w1, x3.y, fmaf(w0, x3.x, acc3))));
        }
    }
    float* dst = ws + m * (NTOK * DD);
    dst[(size_t)(tok0 + 0) * DD + j] = acc0;
    dst[(size_t)(tok0 + 1) * DD + j] = acc1;
    dst[(size_t)(tok0 + 2) * DD + j] = acc2;
    dst[(size_t)(tok0 + 3) * DD + j] = acc3;
    if (m == 1) {
        outK[((size_t)(tok0 + 0) * SS + t) * DD + j] = acc0;
        outK[((size_t)(tok0 + 1) * SS + t) * DD + j] = acc1;
        outK[((size_t)(tok0 + 2) * SS + t) * DD + j] = acc2;
        outK[((size_t)(tok0 + 3) * SS + t) * DD + j] = acc3;
    } else if (m == 2) {
        outV[((size_t)(tok0 + 0) * SS + t) * DD + j] = acc0;
        outV[((size_t)(tok0 + 1) * SS + t) * DD + j] = acc1;
        outV[((size_t)(tok0 + 2) * SS + t) * DD + j] = acc2;
        outV[((size_t)(tok0 + 3) * SS + t) * DD + j] = acc3;
    }
}

// ------- kernel 2: per-token {attention -> out-proj} + copy of V tensor -----
#define K2CB 480     // copy blocks @1024 thr (total 512 blocks = 2/CU exactly)

__global__ __launch_bounds__(1024)
void k2_attn_out_copyV(const float* __restrict__ K, const float* __restrict__ V,
                       const float* __restrict__ Wo, const float* __restrict__ bo,
                       const int* __restrict__ tptr,
                       float* __restrict__ ws,
                       float* __restrict__ outZ, float* __restrict__ outA,
                       float* __restrict__ outV) {
    const int t = *tptr;
    if (blockIdx.x >= NTOK) {
        copy_tensor(V, outV, t, blockIdx.x - NTOK, gridDim.x - NTOK, 1024);
        return;
    }
    const int tok  = blockIdx.x;
    const int tid  = threadIdx.x;
    const int wv   = tid >> 6;               // head
    const int lane = tid & 63;

    __shared__ float qs[DD], ks[DD], vs[DD], zs[DD];
    __shared__ float sc[HH][WINDOW + 8];

    qs[tid] = ws[WS_Q + (size_t)tok * DD + tid];
    ks[tid] = ws[WS_K + (size_t)tok * DD + tid];
    vs[tid] = ws[WS_V + (size_t)tok * DD + tid];
    __syncthreads();

    const int lo    = (t > WINDOW) ? (t - WINDOW) : 0;
    const int count = t - lo + 1;            // <= 65
    const size_t kvbase = (size_t)tok * SS * DD + wv * DEPTH;
    const int hbase = wv * DEPTH;

    // logits for window positions (lane j handles position lo+j)
    for (int jj = lane; jj < count; jj += 64) {
        const int s = lo + jj;
        float acc = 0.f;
        if (s == t) {
            #pragma unroll
            for (int d = 0; d < DEPTH; ++d)
                acc = fmaf(qs[hbase + d], ks[hbase + d], acc);
        } else {
            const f4* kr = (const f4*)(K + kvbase + (size_t)s * DD);
            #pragma unroll
            for (int d4 = 0; d4 < DEPTH / 4; ++d4) {
                const f4 kk = kr[d4];
                acc = fmaf(qs[hbase + d4 * 4 + 0], kk.x, acc);
                acc = fmaf(qs[hbase + d4 * 4 + 1], kk.y, acc);
                acc = fmaf(qs[hbase + d4 * 4 + 2], kk.z, acc);
                acc = fmaf(qs[hbase + d4 * 4 + 3], kk.w, acc);
            }
        }
        sc[wv][jj] = acc * 0.125f;           // 1/sqrt(64)
    }

    // wave softmax (per-wave LDS region; intra-wave ordering)
    float mx = -1e30f;
    for (int jj = lane; jj < count; jj += 64) mx = fmaxf(mx, sc[wv][jj]);
    #pragma unroll
    for (int o = 32; o; o >>= 1) mx = fmaxf(mx, __shfl_xor(mx, o));
    float sum = 0.f;
    for (int jj = lane; jj < count; jj += 64) {
        const float e = expf(sc[wv][jj] - mx);
        sc[wv][jj] = e;
        sum += e;
    }
    #pragma unroll
    for (int o = 32; o; o >>= 1) sum += __shfl_xor(sum, o);
    const float inv = 1.f / sum;
    for (int jj = lane; jj < count; jj += 64) sc[wv][jj] *= inv;

    // full attn row (zeros outside window)
    {
        f4* oa = (f4*)(outA + ((size_t)tok * HH + wv) * SS);
        for (int q4 = lane; q4 < SS / 4; q4 += 64) {
            const int s0 = q4 * 4;
            f4 val;
            val.x = (s0 + 0 >= lo && s0 + 0 <= t) ? sc[wv][s0 + 0 - lo] : 0.f;
            val.y = (s0 + 1 >= lo && s0 + 1 <= t) ? sc[wv][s0 + 1 - lo] : 0.f;
            val.z = (s0 + 2 >= lo && s0 + 2 <= t) ? sc[wv][s0 + 2 - lo] : 0.f;
            val.w = (s0 + 3 >= lo && s0 + 3 <= t) ? sc[wv][s0 + 3 - lo] : 0.f;
            __builtin_nontemporal_store(val, oa + q4);
        }
    }

    // z[head][lane] = sum_s p[s] * V[s][head*64+lane]
    {
        float acc = 0.f;
        #pragma unroll 4
        for (int jj = 0; jj < count - 1; ++jj)
            acc = fmaf(sc[wv][jj], V[kvbase + (size_t)(lo + jj) * DD + lane], acc);
        acc = fmaf(sc[wv][count - 1], vs[hbase + lane], acc);
        zs[hbase + lane] = acc;
    }
    __syncthreads();

    // out-projection: column tid of z @ Wo + bo (coalesced Wo rows)
    {
        float ao = bo[tid];
        #pragma unroll 8
        for (int i2 = 0; i2 < DD; ++i2)
            ao = fmaf(zs[i2], Wo[(size_t)i2 * DD + tid], ao);
        outZ[(size_t)tok * DD + tid] = ao;
    }
}

extern "C" void kernel_launch(void* const* d_in, const int* in_sizes, int n_in,
                              void* d_out, int out_size, void* d_ws, size_t ws_size,
                              hipStream_t stream) {
    const float* x  = (const float*)d_in[0];
    const float* K  = (const float*)d_in[1];
    const float* V  = (const float*)d_in[2];
    const float* Wq = (const float*)d_in[3];
    const float* bq = (const float*)d_in[4];
    const float* Wk = (const float*)d_in[5];
    const float* bk = (const float*)d_in[6];
    const float* Wv = (const float*)d_in[7];
    const float* bv = (const float*)d_in[8];
    const float* Wo = (const float*)d_in[9];
    const float* bo = (const float*)d_in[10];
    const int* tptr = (const int*)d_in[11];

    float* out  = (float*)d_out;
    float* outZ = out;                 // (B,P,1,D)   32,768
    float* outK = out + 32768;         // (B,P,S,D)   67,108,864
    float* outV = outK + KV_ELEMS;     // (B,P,S,D)   67,108,864
    float* outA = outV + KV_ELEMS;     // (B,P,H,1,S) 1,048,576
    float* ws   = (float*)d_ws;

    k1_proj_copyK<<<NPROJ + K1CB, 512, 0, stream>>>(
        x, K, Wq, bq, Wk, bk, Wv, bv, tptr, ws, outK, outV);
    k2_attn_out_copyV<<<NTOK + K2CB, 1024, 0, stream>>>(
        K, V, Wo, bo, tptr, ws, outZ, outA, outV);
}